// Round 1
// baseline (352.920 us; speedup 1.0000x reference)
//
#include <hip/hip_runtime.h>

#define HH 1024
#define WW 1024
#define NBATCH 32
#define ROWS 32
#define NBINS 256

// searchsorted(bins, x, 'left') - 1 with bins[i] = i/256 (exact in fp32).
// t = x*256 is exact (power-of-2 scale). idx = floor(t), minus 1 if t is
// exactly integral (left-side semantics). x==0 -> -1 (dropped).
__device__ inline int bin_of(float x) {
    float t = x * 256.0f;
    int it = (int)t;               // trunc == floor for x >= 0
    if ((float)it == t) it -= 1;
    return it;
}

__device__ inline float wave_red(float v) {
    #pragma unroll
    for (int off = 32; off > 0; off >>= 1) v += __shfl_down(v, off);
    return v;
}

__global__ __launch_bounds__(256, 4) void fused_main(
    const float* __restrict__ E, const float* __restrict__ O,
    unsigned int* __restrict__ gHistE, unsigned int* __restrict__ gHistO,
    double* __restrict__ sums)
{
    const int bt = blockIdx.y;
    const int r0 = blockIdx.x * ROWS;
    const float* __restrict__ e = E + (size_t)bt * HH * WW;
    const float* __restrict__ o = O + (size_t)bt * HH * WW;

    __shared__ unsigned int hE[NBINS];
    __shared__ unsigned int hO[NBINS];
    __shared__ float rbuf[4][5];

    const int tid  = threadIdx.x;
    hE[tid] = 0u;
    hO[tid] = 0u;
    __syncthreads();

    const int lane = tid & 63;
    const int wv   = tid >> 6;
    const int c    = tid * 4;            // 256 threads cover 1024 cols, 4 each
    const bool edgeL    = (lane == 0);
    const bool edgeR    = (lane == 63);
    const bool hasRight = (c + 4 < WW);  // false only for the last quad

    float prvE[4], prvO[4], curE[4], curO[4];
    {
        const float4 a = *reinterpret_cast<const float4*>(e + (size_t)r0 * WW + c);
        curE[0]=a.x; curE[1]=a.y; curE[2]=a.z; curE[3]=a.w;
        const float4 b = *reinterpret_cast<const float4*>(o + (size_t)r0 * WW + c);
        curO[0]=b.x; curO[1]=b.y; curO[2]=b.z; curO[3]=b.w;
        if (r0 > 0) {
            const float4 p = *reinterpret_cast<const float4*>(e + (size_t)(r0-1) * WW + c);
            prvE[0]=p.x; prvE[1]=p.y; prvE[2]=p.z; prvE[3]=p.w;
            const float4 q = *reinterpret_cast<const float4*>(o + (size_t)(r0-1) * WW + c);
            prvO[0]=q.x; prvO[1]=q.y; prvO[2]=q.z; prvO[3]=q.w;
        } else {
            #pragma unroll
            for (int j = 0; j < 4; ++j) { prvE[j] = 0.f; prvO[j] = 0.f; }
        }
    }

    float accL1 = 0.f, accLapE = 0.f, accLapO = 0.f, accDx = 0.f, accDy = 0.f;

    for (int r = r0; r < r0 + ROWS; ++r) {
        const int rn = r + 1;
        float nxtE[4], nxtO[4];
        if (rn < HH) {
            const float4 a = *reinterpret_cast<const float4*>(e + (size_t)rn * WW + c);
            nxtE[0]=a.x; nxtE[1]=a.y; nxtE[2]=a.z; nxtE[3]=a.w;
            const float4 b = *reinterpret_cast<const float4*>(o + (size_t)rn * WW + c);
            nxtO[0]=b.x; nxtO[1]=b.y; nxtO[2]=b.z; nxtO[3]=b.w;
        } else {
            #pragma unroll
            for (int j = 0; j < 4; ++j) { nxtE[j] = 0.f; nxtO[j] = 0.f; }
        }

        // horizontal neighbors via intra-wave shuffles; wave-edge lanes fall
        // back to (cached) scalar loads; image edges -> zero padding
        float lE = __shfl_up(curE[3], 1);
        float rE = __shfl_down(curE[0], 1);
        float lO = __shfl_up(curO[3], 1);
        float rO = __shfl_down(curO[0], 1);
        if (edgeL) {
            lE = (c > 0) ? e[(size_t)r * WW + c - 1] : 0.f;
            lO = (c > 0) ? o[(size_t)r * WW + c - 1] : 0.f;
        }
        if (edgeR) {
            rE = hasRight ? e[(size_t)r * WW + c + 4] : 0.f;
            rO = hasRight ? o[(size_t)r * WW + c + 4] : 0.f;
        }

        #pragma unroll
        for (int j = 0; j < 4; ++j) {
            const float le = (j == 0) ? lE : curE[j-1];
            const float re = (j == 3) ? rE : curE[j+1];
            accLapE += fabsf(prvE[j] + nxtE[j] + le + re - 4.f * curE[j]);
            const float lo = (j == 0) ? lO : curO[j-1];
            const float ro = (j == 3) ? rO : curO[j+1];
            accLapO += fabsf(prvO[j] + nxtO[j] + lo + ro - 4.f * curO[j]);
            accL1 += fabsf(curE[j] - curO[j]);
            const int be = bin_of(curE[j]);
            if (be >= 0 && be < NBINS) atomicAdd(&hE[be], 1u);
            const int bo = bin_of(curO[j]);
            if (bo >= 0 && bo < NBINS) atomicAdd(&hO[bo], 1u);
        }

        if (rn < HH) {
            #pragma unroll
            for (int j = 0; j < 4; ++j) accDx += fabsf(nxtE[j] - curE[j]);
        }
        accDy += fabsf(curE[1]-curE[0]) + fabsf(curE[2]-curE[1]) + fabsf(curE[3]-curE[2]);
        if (hasRight) accDy += fabsf(rE - curE[3]);

        #pragma unroll
        for (int j = 0; j < 4; ++j) {
            prvE[j] = curE[j]; curE[j] = nxtE[j];
            prvO[j] = curO[j]; curO[j] = nxtO[j];
        }
    }

    // block-reduce the 5 scalars, one fp64 atomic each per block
    float acc[5] = {accL1, accLapE, accLapO, accDx, accDy};
    #pragma unroll
    for (int k = 0; k < 5; ++k) {
        const float w = wave_red(acc[k]);
        if (lane == 0) rbuf[wv][k] = w;
    }
    __syncthreads();
    if (tid == 0) {
        #pragma unroll
        for (int k = 0; k < 5; ++k) {
            const double tot = (double)rbuf[0][k] + rbuf[1][k] + rbuf[2][k] + rbuf[3][k];
            atomicAdd(&sums[k], tot);
        }
    }

    // flush per-block histograms (tid == bin index)
    atomicAdd(&gHistE[bt * NBINS + tid], hE[tid]);
    atomicAdd(&gHistO[bt * NBINS + tid], hO[tid]);
}

__global__ __launch_bounds__(256) void finalize(
    const unsigned int* __restrict__ gHistE, const unsigned int* __restrict__ gHistO,
    const double* __restrict__ sums, float* __restrict__ out)
{
    __shared__ double sred[8];
    const int tid  = threadIdx.x;
    const int lane = tid & 63;
    const int wv   = tid >> 6;

    double hacc = 0.0;
    for (int bt = 0; bt < NBATCH; ++bt) {
        const double ce = (double)gHistE[bt * NBINS + tid];
        const double co = (double)gHistO[bt * NBINS + tid];
        double te = ce, to = co;
        #pragma unroll
        for (int off = 32; off > 0; off >>= 1) {
            te += __shfl_down(te, off);
            to += __shfl_down(to, off);
        }
        if (lane == 0) { sred[wv] = te; sred[4 + wv] = to; }
        __syncthreads();
        te = sred[0] + sred[1] + sred[2] + sred[3];
        to = sred[4] + sred[5] + sred[6] + sred[7];
        __syncthreads();
        const double he = (ce + 1e-6) / (te + 1e-6);
        const double ho = (co + 1e-6) / (to + 1e-6);
        const double d  = he - ho;
        hacc += d * d;
    }
    #pragma unroll
    for (int off = 32; off > 0; off >>= 1) hacc += __shfl_down(hacc, off);
    if (lane == 0) sred[wv] = hacc;
    __syncthreads();

    if (tid == 0) {
        const double hsum  = sred[0] + sred[1] + sred[2] + sred[3];
        const double hist  = hsum / ((double)NBATCH * NBINS) / (double)NBINS;
        const double N     = (double)NBATCH * HH * WW;
        const double l1    = sums[0] / N;
        const double cE    = sums[1] / N;
        const double cO    = sums[2] / N;
        const double cont  = fabs(cE - cO) / (cO + 1e-6);
        const double dxm   = sums[3] / ((double)NBATCH * (HH - 1) * WW);
        const double dym   = sums[4] / ((double)NBATCH * HH * (WW - 1));
        out[0] = (float)(l1 + 0.1 * hist + 0.1 * cont + 0.01 * (dxm + dym));
    }
}

extern "C" void kernel_launch(void* const* d_in, const int* in_sizes, int n_in,
                              void* d_out, int out_size, void* d_ws, size_t ws_size,
                              hipStream_t stream)
{
    const float* E = (const float*)d_in[0];  // enhanced_y
    const float* O = (const float*)d_in[1];  // original_y
    float* out = (float*)d_out;

    unsigned int* gHistE = (unsigned int*)d_ws;
    unsigned int* gHistO = gHistE + NBATCH * NBINS;
    double* sums = (double*)((char*)d_ws + (size_t)2 * NBATCH * NBINS * sizeof(unsigned int));

    // ws is poisoned 0xAA before every timed call -> zero the parts we use
    hipMemsetAsync(d_ws, 0,
                   (size_t)2 * NBATCH * NBINS * sizeof(unsigned int) + 8 * sizeof(double),
                   stream);

    dim3 grid(HH / ROWS, NBATCH);
    fused_main<<<grid, 256, 0, stream>>>(E, O, gHistE, gHistO, sums);
    finalize<<<1, 256, 0, stream>>>(gHistE, gHistO, sums, out);
}